// Round 6
// baseline (359.878 us; speedup 1.0000x reference)
//
#include <hip/hip_runtime.h>
#include <math.h>

#pragma clang fp contract(off)

#define NB 16
#define NC 80
#define NTOT 17064
#define TOPK 1000
#define NBINS 8192
#define CAP 4096
#define MAXDET 100
#define NREP 2           // histogram replicas (spread flush atomics)
#define CNTSTRIDE 64     // u32 stride between per-batch counters = 256 B
#define BIGCAP 245760    // per-batch candidate capacity (~199k expected, 100+ sigma headroom)

struct Ptrs {
    const float* lg[5];
    const float* bb[5];
    const float* ct[5];
};

__device__ __forceinline__ void level_of(int n, int& l, int& hw, int& W,
                                         int& stride, int& half, int& HW) {
    if (n < 12800)      { l = 0; hw = n;         W = 128; stride = 8;   half = 4;  HW = 12800; }
    else if (n < 16000) { l = 1; hw = n - 12800; W = 64;  stride = 16;  half = 8;  HW = 3200;  }
    else if (n < 16800) { l = 2; hw = n - 16000; W = 32;  stride = 32;  half = 16; HW = 800;   }
    else if (n < 17008) { l = 3; hw = n - 16800; W = 16;  stride = 64;  half = 32; HW = 208;   }
    else                { l = 4; hw = n - 17008; W = 8;   stride = 128; half = 64; HW = 56;    }
}

// ---------------- pass 1: fused histogram + candidate append ----------------
// Linear float4 sweep per level (compile-time constants). LDS-private hist.
// WRITE: append every candidate (cls>0.05) key to bigbuf via BLOCK-aggregated
// atomics on a 256B-padded per-batch counter (parity-buffered LDS staging).
template<int HW4, int NF4, int LVOFF, bool WRITE>
__device__ __forceinline__ void sweep_level(const float* lgb, const float* ctb,
        int tid, int lane, int wv, int bx, int gx, unsigned* lh,
        unsigned* cntb, unsigned long long* bigb, unsigned long long ltmask,
        unsigned (*lag)[8], int& m) {
    for (int i0 = bx * 256; i0 < NF4; i0 += gx * 256) {
        int i = i0 + tid;
        bool f0 = false, f1 = false, f2 = false, f3 = false;
        unsigned long long k0 = 0, k1 = 0, k2 = 0, k3 = 0;
        if (i < NF4) {
            int c   = i / HW4;            // constant divisor -> magic mul
            int hwf = i - c * HW4;
            float4 v = *(const float4*)(lgb + c * (HW4 * 4) + hwf * 4);
            if (v.x > -2.95f || v.y > -2.95f || v.z > -2.95f || v.w > -2.95f) {
                float4 cv = *(const float4*)(ctb + hwf * 4);
                int nbase = LVOFF + hwf * 4;
#define DO_J(J, X, CT, F, K)                                                  \
                if ((X) > -2.95f) {            /* logit(0.05) = -2.9444 */    \
                    float cls = 1.0f / (1.0f + expf(-(X)));                   \
                    if (cls > 0.05f) {                                        \
                        float cen = 1.0f / (1.0f + expf(-(CT)));              \
                        float comb = cls * cen;                               \
                        unsigned bits = __float_as_uint(comb);                \
                        atomicAdd(&lh[bits >> 19], 1u);                       \
                        if (WRITE) {                                          \
                            unsigned idx = (unsigned)((nbase + (J)) * NC + c);\
                            K = ((unsigned long long)bits << 32) |            \
                                (0xFFFFFFFFu - idx);                          \
                            F = true;                                         \
                        }                                                     \
                    }                                                         \
                }
                DO_J(0, v.x, cv.x, f0, k0)
                DO_J(1, v.y, cv.y, f1, k1)
                DO_J(2, v.z, cv.z, f2, k2)
                DO_J(3, v.w, cv.w, f3, k3)
#undef DO_J
            }
        }
        if (WRITE) {
            unsigned long long m0 = __ballot(f0), m1 = __ballot(f1);
            unsigned long long m2 = __ballot(f2), m3 = __ballot(f3);
            unsigned t0 = (unsigned)__popcll(m0), t1 = (unsigned)__popcll(m1);
            unsigned t2 = (unsigned)__popcll(m2), t3 = (unsigned)__popcll(m3);
            unsigned wtot = t0 + t1 + t2 + t3;
            int p = m & 1; ++m;
            if (lane == 0) lag[p][wv] = wtot;
            __syncthreads();
            if (tid == 0) {
                unsigned tt = lag[p][0] + lag[p][1] + lag[p][2] + lag[p][3];
                lag[p][4] = tt ? atomicAdd(cntb, tt) : 0u;
            }
            __syncthreads();
            unsigned base = lag[p][4];
            for (int q = 0; q < wv; ++q) base += lag[p][q];
            if (f0) { unsigned pos = base + (unsigned)__popcll(m0 & ltmask);               if (pos < BIGCAP) bigb[pos] = k0; }
            if (f1) { unsigned pos = base + t0 + (unsigned)__popcll(m1 & ltmask);          if (pos < BIGCAP) bigb[pos] = k1; }
            if (f2) { unsigned pos = base + t0 + t1 + (unsigned)__popcll(m2 & ltmask);     if (pos < BIGCAP) bigb[pos] = k2; }
            if (f3) { unsigned pos = base + t0 + t1 + t2 + (unsigned)__popcll(m3 & ltmask);if (pos < BIGCAP) bigb[pos] = k3; }
        }
    }
}

template<bool WRITE>
__global__ void __launch_bounds__(256) k_score1(Ptrs p, unsigned* hist,
                                                unsigned* cnt1,
                                                unsigned long long* bigbuf) {
    __shared__ unsigned lh[NBINS];   // 32 KiB
    __shared__ unsigned lag[2][8];
    int b = blockIdx.y, tid = threadIdx.x, bx = blockIdx.x, gx = gridDim.x;
    int lane = tid & 63, wv = tid >> 6;
    unsigned long long ltmask = (1ULL << lane) - 1ULL;
    for (int i = tid; i < NBINS; i += 256) lh[i] = 0;
    __syncthreads();

    unsigned* cntb = cnt1 + (size_t)b * CNTSTRIDE;
    unsigned long long* bigb = bigbuf + (size_t)b * BIGCAP;
    int m = 0;

    sweep_level<3200, 256000,     0, WRITE>(p.lg[0] + (size_t)b * NC * 12800, p.ct[0] + (size_t)b * 12800, tid, lane, wv, bx, gx, lh, cntb, bigb, ltmask, lag, m);
    sweep_level< 800,  64000, 12800, WRITE>(p.lg[1] + (size_t)b * NC * 3200,  p.ct[1] + (size_t)b * 3200,  tid, lane, wv, bx, gx, lh, cntb, bigb, ltmask, lag, m);
    sweep_level< 200,  16000, 16000, WRITE>(p.lg[2] + (size_t)b * NC * 800,   p.ct[2] + (size_t)b * 800,   tid, lane, wv, bx, gx, lh, cntb, bigb, ltmask, lag, m);
    sweep_level<  52,   4160, 16800, WRITE>(p.lg[3] + (size_t)b * NC * 208,   p.ct[3] + (size_t)b * 208,   tid, lane, wv, bx, gx, lh, cntb, bigb, ltmask, lag, m);
    sweep_level<  14,   1120, 17008, WRITE>(p.lg[4] + (size_t)b * NC * 56,    p.ct[4] + (size_t)b * 56,    tid, lane, wv, bx, gx, lh, cntb, bigb, ltmask, lag, m);

    __syncthreads();
    unsigned* h = hist + ((size_t)(bx & (NREP - 1)) * NB + b) * NBINS;
    for (int i = tid; i < NBINS; i += 256) {
        unsigned v = lh[i];
        if (v) atomicAdd(&h[i], v);
    }
}

// ---------------- threshold: highest bin with suffix count >= TOPK ----------
// Wave-shuffle suffix scan: 3 barriers total.
__global__ void __launch_bounds__(256) k_thresh(const unsigned* hist, unsigned* T) {
    __shared__ unsigned hl[NBINS];
    __shared__ unsigned wtot[4];
    __shared__ int Tf;
    int b = blockIdx.x, tid = threadIdx.x, lane = tid & 63, wv = tid >> 6;
    if (tid == 0) Tf = 0;
    for (int i = tid; i < NBINS; i += 256) {
        unsigned s = 0;
        for (int r = 0; r < NREP; ++r)
            s += hist[((size_t)r * NB + b) * NBINS + i];
        hl[i] = s;
    }
    __syncthreads();
    int base = tid * 32;
    unsigned mysum = 0;
#pragma unroll
    for (int i = 0; i < 32; ++i) mysum += hl[base + i];
    unsigned incl = mysum;                      // suffix-inclusive within wave
#pragma unroll
    for (int off = 1; off < 64; off <<= 1) {
        unsigned v = __shfl_down(incl, off);
        if (lane + off < 64) incl += v;
    }
    if (lane == 0) wtot[wv] = incl;             // whole-wave total
    __syncthreads();
    unsigned above = 0;
    for (int w = wv + 1; w < 4; ++w) above += wtot[w];
    unsigned sufincl = incl + above;            // sum of chunks >= tid
    unsigned excl = sufincl - mysum;            // sum of chunks >  tid
    if (excl < TOPK && sufincl >= TOPK) {
        unsigned running = excl;
        for (int bin = base + 31; bin >= base; --bin) {
            running += hl[bin];
            if (running >= TOPK) { Tf = bin; break; }
        }
    }
    __syncthreads();
    if (tid == 0) T[b] = (unsigned)Tf;
}

// ---------------- filter: keep bins >= T from bigbuf ------------------------
__global__ void __launch_bounds__(256) k_filter(const unsigned* cnt1, const unsigned* T,
                                                const unsigned long long* bigbuf,
                                                unsigned* cnt2, unsigned long long* sel) {
    __shared__ unsigned lag[2][8];
    int b = blockIdx.y, tid = threadIdx.x, lane = tid & 63, wv = tid >> 6;
    int bx = blockIdx.x, gx = gridDim.x;
    unsigned M = cnt1[(size_t)b * CNTSTRIDE];
    if (M > BIGCAP) M = BIGCAP;
    unsigned Tb = T[b];
    const unsigned long long* src = bigbuf + (size_t)b * BIGCAP;
    unsigned long long* dst = sel + (size_t)b * CAP;
    unsigned long long ltmask = (1ULL << lane) - 1ULL;
    int m = 0;
    for (int i0 = bx * 256; i0 < (int)M; i0 += gx * 256) {
        int i = i0 + tid;
        unsigned long long key = 0;
        bool f = false;
        if (i < (int)M) {
            key = src[i];
            f = ((unsigned)(key >> 51) >= Tb);   // key>>51 == score_bits>>19
        }
        unsigned long long mk = __ballot(f);
        unsigned wtot = (unsigned)__popcll(mk);
        int p = m & 1; ++m;
        if (lane == 0) lag[p][wv] = wtot;
        __syncthreads();
        if (tid == 0) {
            unsigned tt = lag[p][0] + lag[p][1] + lag[p][2] + lag[p][3];
            lag[p][4] = tt ? atomicAdd(&cnt2[(size_t)b * CNTSTRIDE], tt) : 0u;
        }
        __syncthreads();
        unsigned basep = lag[p][4];
        for (int q = 0; q < wv; ++q) basep += lag[p][q];
        if (f) {
            unsigned pos = basep + (unsigned)__popcll(mk & ltmask);
            if (pos < CAP) dst[pos] = key;
        }
    }
}

// ---------------- fallback (small ws): recompute-compact from logits --------
template<int HW4, int NF4, int LVOFF>
__device__ __forceinline__ void compact_level(const float* lgb, const float* ctb,
        int tid, int lane, int bx, int gx, unsigned Tb, float xpre,
        unsigned* cntb, unsigned long long* selb, unsigned long long ltmask) {
    for (int i0 = bx * 256; i0 < NF4; i0 += gx * 256) {
        int i = i0 + tid;
        bool f0 = false, f1 = false, f2 = false, f3 = false;
        unsigned long long k0 = 0, k1 = 0, k2 = 0, k3 = 0;
        if (i < NF4) {
            int c   = i / HW4;
            int hwf = i - c * HW4;
            float4 v = *(const float4*)(lgb + c * (HW4 * 4) + hwf * 4);
            if (v.x > xpre || v.y > xpre || v.z > xpre || v.w > xpre) {
                float4 cv = *(const float4*)(ctb + hwf * 4);
                int nbase = LVOFF + hwf * 4;
#define DO_J(J, X, CT, F, K)                                                  \
                if ((X) > xpre) {                                             \
                    float cls = 1.0f / (1.0f + expf(-(X)));                   \
                    if (cls > 0.05f) {                                        \
                        float cen = 1.0f / (1.0f + expf(-(CT)));              \
                        float comb = cls * cen;                               \
                        unsigned bits = __float_as_uint(comb);                \
                        if ((bits >> 19) >= Tb) {                             \
                            unsigned idx = (unsigned)((nbase + (J)) * NC + c);\
                            K = ((unsigned long long)bits << 32) |            \
                                (0xFFFFFFFFu - idx);                          \
                            F = true;                                         \
                        }                                                     \
                    }                                                         \
                }
                DO_J(0, v.x, cv.x, f0, k0)
                DO_J(1, v.y, cv.y, f1, k1)
                DO_J(2, v.z, cv.z, f2, k2)
                DO_J(3, v.w, cv.w, f3, k3)
#undef DO_J
            }
        }
        unsigned long long m0 = __ballot(f0), m1 = __ballot(f1);
        unsigned long long m2 = __ballot(f2), m3 = __ballot(f3);
        if ((m0 | m1 | m2 | m3) == 0ULL) continue;
        unsigned t0 = (unsigned)__popcll(m0), t1 = (unsigned)__popcll(m1);
        unsigned t2 = (unsigned)__popcll(m2), t3 = (unsigned)__popcll(m3);
        unsigned total = t0 + t1 + t2 + t3;
        int basep = 0;
        if (lane == 0) basep = (int)atomicAdd(cntb, total);
        basep = __shfl(basep, 0);
        if (f0) { int pos = basep + (int)__popcll(m0 & ltmask);                       if (pos < CAP) selb[pos] = k0; }
        if (f1) { int pos = basep + (int)t0 + (int)__popcll(m1 & ltmask);             if (pos < CAP) selb[pos] = k1; }
        if (f2) { int pos = basep + (int)(t0 + t1) + (int)__popcll(m2 & ltmask);      if (pos < CAP) selb[pos] = k2; }
        if (f3) { int pos = basep + (int)(t0 + t1 + t2) + (int)__popcll(m3 & ltmask); if (pos < CAP) selb[pos] = k3; }
    }
}

__global__ void __launch_bounds__(256) k_compactB(Ptrs p, const unsigned* T,
                                                  unsigned* cnt2, unsigned long long* sel) {
    int b = blockIdx.y, tid = threadIdx.x, lane = tid & 63;
    int bx = blockIdx.x, gx = gridDim.x;
    unsigned Tb = T[b];
    float mthr = __uint_as_float(Tb << 19);
    float xpre = -2.95f;
    if (mthr > 1e-37f && mthr < 1.0f) {
        float lm = logf(mthr / (1.0f - mthr)) - 0.01f;
        if (lm > xpre) xpre = lm;
    }
    unsigned long long ltmask = (1ULL << lane) - 1ULL;
    unsigned* cntb = cnt2 + (size_t)b * CNTSTRIDE;
    unsigned long long* selb = sel + (size_t)b * CAP;
    compact_level<3200, 256000,     0>(p.lg[0] + (size_t)b * NC * 12800, p.ct[0] + (size_t)b * 12800, tid, lane, bx, gx, Tb, xpre, cntb, selb, ltmask);
    compact_level< 800,  64000, 12800>(p.lg[1] + (size_t)b * NC * 3200,  p.ct[1] + (size_t)b * 3200,  tid, lane, bx, gx, Tb, xpre, cntb, selb, ltmask);
    compact_level< 200,  16000, 16000>(p.lg[2] + (size_t)b * NC * 800,   p.ct[2] + (size_t)b * 800,   tid, lane, bx, gx, Tb, xpre, cntb, selb, ltmask);
    compact_level<  52,   4160, 16800>(p.lg[3] + (size_t)b * NC * 208,   p.ct[3] + (size_t)b * 208,   tid, lane, bx, gx, Tb, xpre, cntb, selb, ltmask);
    compact_level<  14,   1120, 17008>(p.lg[4] + (size_t)b * NC * 56,    p.ct[4] + (size_t)b * 56,    tid, lane, bx, gx, Tb, xpre, cntb, selb, ltmask);
}

// ---------------- fused select(sort) + decode + greedy NMS ------------------
// 256 threads, one block/batch. Bitonic sort (desc) of <=CAP keys gives exact
// lax.top_k order. Thread tid owns ranks 4tid..4tid+3 in REGISTERS; argmax ==
// min alive rank via one ballot + in-wave shfl; ONE barrier per NMS iteration
// (parity-buffered wmin).
__global__ void __launch_bounds__(256) k_selnms(Ptrs p, const unsigned* cnt,
                                                const unsigned long long* sel,
                                                const float* im_info, float* out) {
    __shared__ unsigned long long keys[CAP];   // 32 KiB
    __shared__ float4 nbx[1024];
    __shared__ float  sarea[1024];
    __shared__ float4 obox[1024];
    __shared__ float2 oscl[1024];
    __shared__ unsigned wmin[2][4];
    int b = blockIdx.x, tid = threadIdx.x;
    int lane = tid & 63, wv = tid >> 6;

    unsigned M = cnt[(size_t)b * CNTSTRIDE];
    if (M > CAP) M = CAP;
    for (int i = tid; i < CAP; i += 256)
        keys[i] = (i < (int)M) ? sel[(size_t)b * CAP + i] : 0ULL;
    __syncthreads();

    int NS = 1024;
    while (NS < (int)M) NS <<= 1;
    for (int k = 2; k <= NS; k <<= 1) {
        for (int j = k >> 1; j > 0; j >>= 1) {
            for (int i = tid; i < NS; i += 256) {
                int ixj = i ^ j;
                if (ixj > i) {
                    unsigned long long va = keys[i], vb = keys[ixj];
                    bool desc = ((i & k) == 0);
                    if (desc ? (va < vb) : (va > vb)) { keys[i] = vb; keys[ixj] = va; }
                }
            }
            __syncthreads();
        }
    }

    // decode ranks 4tid+j into registers + LDS lookup tables
    float Him = im_info[b * 2 + 0], Wim = im_info[b * 2 + 1];
    float xmax = Wim - 1.0f, ymax = Him - 1.0f;
    unsigned amask = 0;
    float4 nbr[4];
    float  ar[4];
#pragma unroll
    for (int j = 0; j < 4; ++j) {
        int r = 4 * tid + j;
        nbr[j] = make_float4(0.f, 0.f, 0.f, 0.f);
        ar[j] = 0.f;
        unsigned long long key = keys[r];
        if (r < TOPK && key != 0ULL) {
            unsigned sb = (unsigned)(key >> 32);
            unsigned idx = 0xFFFFFFFFu - (unsigned)(key & 0xFFFFFFFFu);
            float val = __uint_as_float(sb);
            int n = idx / NC, c = idx - n * NC;
            int l, hw, W, stride, half, HW;
            level_of(n, l, hw, W, stride, half, HW);
            int wx = hw % W, hy = hw / W;
            float locx = (float)(wx * stride + half);
            float locy = (float)(hy * stride + half);
            const float* bb = p.bb[l] + (size_t)b * 4 * HW + hw;
            float r0 = bb[0], r1 = bb[(size_t)HW], r2 = bb[(size_t)2 * HW], r3 = bb[(size_t)3 * HW];
            float x1 = locx - r0, y1 = locy - r1, x2 = locx + r2, y2 = locy + r3;
            x1 = fminf(fmaxf(x1, 0.f), xmax);
            y1 = fminf(fmaxf(y1, 0.f), ymax);
            x2 = fminf(fmaxf(x2, 0.f), xmax);
            y2 = fminf(fmaxf(y2, 0.f), ymax);
            float s = sqrtf(val + 1e-12f);
            float off = (float)c * 10000.0f;
            float a0 = x1 + off, a1 = y1 + off, a2 = x2 + off, a3 = y2 + off;
            nbr[j] = make_float4(a0, a1, a2, a3);
            ar[j]  = fmaxf(a2 - a0, 0.f) * fmaxf(a3 - a1, 0.f);
            nbx[r] = nbr[j];
            sarea[r] = ar[j];
            obox[r] = make_float4(x1, y1, x2, y2);
            oscl[r] = make_float2(s, (float)c);
            amask |= (1u << j);
        }
    }
    __syncthreads();

    bool have = false;
    float4 pb = make_float4(0.f, 0.f, 0.f, 0.f);
    float pa = 0.f;
    for (int it = 0; it < MAXDET; ++it) {
        if (have && amask) {
#pragma unroll
            for (int j = 0; j < 4; ++j) {
                if (amask & (1u << j)) {
                    float xx1 = fmaxf(pb.x, nbr[j].x);
                    float yy1 = fmaxf(pb.y, nbr[j].y);
                    float xx2 = fminf(pb.z, nbr[j].z);
                    float yy2 = fminf(pb.w, nbr[j].w);
                    float inter = fmaxf(xx2 - xx1, 0.f) * fmaxf(yy2 - yy1, 0.f);
                    float iou = inter / (((pa + ar[j]) - inter) + 1e-9f);
                    if (iou >= 0.6f) amask &= ~(1u << j);
                }
            }
        }
        unsigned long long wb = __ballot(amask != 0);
        int pparity = it & 1;
        int mt = wb ? __builtin_ctzll(wb) : 0;
        unsigned am2 = (unsigned)__shfl((int)amask, mt);   // min-tid thread's mask
        if (lane == 0) {
            unsigned r = wb ? (unsigned)((wv * 64 + mt) * 4 + __builtin_ctz(am2))
                            : 0xFFFFFFFFu;
            wmin[pparity][wv] = r;
        }
        __syncthreads();
        unsigned best = wmin[pparity][0];
        best = min(best, wmin[pparity][1]);
        best = min(best, wmin[pparity][2]);
        best = min(best, wmin[pparity][3]);
        float* o6 = out + ((size_t)b * MAXDET + it) * 6;
        if (best != 0xFFFFFFFFu) {
            pb = nbx[best];                    // LDS broadcast read
            pa = sarea[best];
            have = true;
            if ((unsigned)tid == (best >> 2)) amask &= ~(1u << (best & 3u));
            if (tid == 0) {
                float4 ob = obox[best]; float2 sc2 = oscl[best];
                o6[0] = ob.x; o6[1] = ob.y; o6[2] = ob.z; o6[3] = ob.w;
                o6[4] = sc2.x; o6[5] = sc2.y;
            }
        } else {
            have = false;
            if (tid == 0) {
                o6[0] = 0.f; o6[1] = 0.f; o6[2] = 0.f;
                o6[3] = 0.f; o6[4] = 0.f; o6[5] = 0.f;
            }
        }
        // no second barrier needed: wmin is parity-buffered, nbx/obox read-only
    }
}

extern "C" void kernel_launch(void* const* d_in, const int* in_sizes, int n_in,
                              void* d_out, int out_size, void* d_ws, size_t ws_size,
                              hipStream_t stream) {
    Ptrs p;
    for (int l = 0; l < 5; ++l) {
        p.lg[l] = (const float*)d_in[3 * l + 0];
        p.bb[l] = (const float*)d_in[3 * l + 1];
        p.ct[l] = (const float*)d_in[3 * l + 2];
    }
    const float* im_info = (const float*)d_in[15];
    float* out = (float*)d_out;

    unsigned char* w = (unsigned char*)d_ws;
    // layout: [hist 1,048,576 | cnt1 4096 | cnt2 4096 | T 256] zeroed,
    //         sel 524,288 | bigbuf 31,457,280  -> total 33,038,592
    unsigned* hist             = (unsigned*)(w);
    unsigned* cnt1             = (unsigned*)(w + 1048576);
    unsigned* cnt2             = (unsigned*)(w + 1052672);
    unsigned* T                = (unsigned*)(w + 1056768);
    unsigned long long* sel    = (unsigned long long*)(w + 1057024);
    unsigned long long* bigbuf = (unsigned long long*)(w + 1581312);

    const bool big = ws_size >= (size_t)33038592;

    hipMemsetAsync(w, 0, 1057024, stream);

    if (big) {
        k_score1<true ><<<dim3(64, NB), 256, 0, stream>>>(p, hist, cnt1, bigbuf);
        k_thresh<<<NB, 256, 0, stream>>>(hist, T);
        k_filter<<<dim3(32, NB), 256, 0, stream>>>(cnt1, T, bigbuf, cnt2, sel);
    } else {
        k_score1<false><<<dim3(64, NB), 256, 0, stream>>>(p, hist, cnt1, nullptr);
        k_thresh<<<NB, 256, 0, stream>>>(hist, T);
        k_compactB<<<dim3(128, NB), 256, 0, stream>>>(p, T, cnt2, sel);
    }
    k_selnms<<<NB, 256, 0, stream>>>(p, cnt2, sel, im_info, out);
}

// Round 7
// 264.357 us; speedup vs baseline: 1.3613x; 1.3613x over previous
//
#include <hip/hip_runtime.h>
#include <math.h>

#pragma clang fp contract(off)

#define NB 16
#define NC 80
#define NTOT 17064
#define TOPK 1000
#define NBINS 8192
#define CAP 4096
#define MAXDET 100
#define NREP 4           // histogram replicas (spread flush atomics)
#define CNTSTRIDE 64     // u32 stride between per-batch counters = 256 B

struct Ptrs {
    const float* lg[5];
    const float* bb[5];
    const float* ct[5];
};

__device__ __forceinline__ void level_of(int n, int& l, int& hw, int& W,
                                         int& stride, int& half, int& HW) {
    if (n < 12800)      { l = 0; hw = n;         W = 128; stride = 8;   half = 4;  HW = 12800; }
    else if (n < 16000) { l = 1; hw = n - 12800; W = 64;  stride = 16;  half = 8;  HW = 3200;  }
    else if (n < 16800) { l = 2; hw = n - 16000; W = 32;  stride = 32;  half = 16; HW = 800;   }
    else if (n < 17008) { l = 3; hw = n - 16800; W = 16;  stride = 64;  half = 32; HW = 208;   }
    else                { l = 4; hw = n - 17008; W = 8;   stride = 128; half = 64; HW = 56;    }
}

// ---------------- pass 1: histogram sweep (per-level, compile-time const) ---
template<int HW4, int NF4>
__device__ __forceinline__ void hist_level(const float* lgb, const float* ctb,
                                           int tid, int bx, int gx, unsigned* lh) {
    for (int i0 = bx * 256; i0 < NF4; i0 += gx * 256) {
        int i = i0 + tid;
        if (i < NF4) {
            int c   = i / HW4;            // constant divisor -> magic mul
            int hwf = i - c * HW4;
            float4 v  = *(const float4*)(lgb + c * (HW4 * 4) + hwf * 4);
            if (v.x > -2.95f || v.y > -2.95f || v.z > -2.95f || v.w > -2.95f) {
                float4 cv = *(const float4*)(ctb + hwf * 4);
                float xs[4] = {v.x, v.y, v.z, v.w};
                float cs[4] = {cv.x, cv.y, cv.z, cv.w};
#pragma unroll
                for (int j = 0; j < 4; ++j) {
                    float x = xs[j];
                    if (x > -2.95f) {             // logit(0.05) = -2.9444
                        float cls = 1.0f / (1.0f + expf(-x));
                        if (cls > 0.05f) {
                            float cen = 1.0f / (1.0f + expf(-cs[j]));
                            float comb = cls * cen;
                            atomicAdd(&lh[__float_as_uint(comb) >> 19], 1u);
                        }
                    }
                }
            }
        }
    }
}

__global__ void __launch_bounds__(256) k_histA(Ptrs p, unsigned* hist) {
    __shared__ unsigned lh[NBINS];   // 32 KiB
    int b = blockIdx.y, tid = threadIdx.x, bx = blockIdx.x, gx = gridDim.x;
    for (int i = tid; i < NBINS; i += 256) lh[i] = 0;
    __syncthreads();

    hist_level<3200, 256000>(p.lg[0] + (size_t)b * NC * 12800, p.ct[0] + (size_t)b * 12800, tid, bx, gx, lh);
    hist_level< 800,  64000>(p.lg[1] + (size_t)b * NC * 3200,  p.ct[1] + (size_t)b * 3200,  tid, bx, gx, lh);
    hist_level< 200,  16000>(p.lg[2] + (size_t)b * NC * 800,   p.ct[2] + (size_t)b * 800,   tid, bx, gx, lh);
    hist_level<  52,   4160>(p.lg[3] + (size_t)b * NC * 208,   p.ct[3] + (size_t)b * 208,   tid, bx, gx, lh);
    hist_level<  14,   1120>(p.lg[4] + (size_t)b * NC * 56,    p.ct[4] + (size_t)b * 56,    tid, bx, gx, lh);

    __syncthreads();
    unsigned* h = hist + ((size_t)(bx & (NREP - 1)) * NB + b) * NBINS;
    for (int i = tid; i < NBINS; i += 256) {
        unsigned v = lh[i];
        if (v) atomicAdd(&h[i], v);
    }
}

// ---------------- threshold: highest bin with suffix count >= TOPK ----------
__global__ void __launch_bounds__(256) k_thresh(const unsigned* hist, unsigned* T) {
    __shared__ unsigned hl[NBINS];
    __shared__ unsigned wtot[4];
    __shared__ int Tf;
    int b = blockIdx.x, tid = threadIdx.x, lane = tid & 63, wv = tid >> 6;
    if (tid == 0) Tf = 0;
    for (int i = tid; i < NBINS; i += 256) {
        unsigned s = 0;
        for (int r = 0; r < NREP; ++r)
            s += hist[((size_t)r * NB + b) * NBINS + i];
        hl[i] = s;
    }
    __syncthreads();
    int base = tid * 32;
    unsigned mysum = 0;
#pragma unroll
    for (int i = 0; i < 32; ++i) mysum += hl[base + i];
    unsigned incl = mysum;                      // suffix-inclusive within wave
#pragma unroll
    for (int off = 1; off < 64; off <<= 1) {
        unsigned v = __shfl_down(incl, off);
        if (lane + off < 64) incl += v;
    }
    if (lane == 0) wtot[wv] = incl;             // whole-wave total
    __syncthreads();
    unsigned above = 0;
    for (int w = wv + 1; w < 4; ++w) above += wtot[w];
    unsigned sufincl = incl + above;            // sum of chunks >= tid
    unsigned excl = sufincl - mysum;            // sum of chunks >  tid
    if (excl < TOPK && sufincl >= TOPK) {
        unsigned running = excl;
        for (int bin = base + 31; bin >= base; --bin) {
            running += hl[bin];
            if (running >= TOPK) { Tf = bin; break; }
        }
    }
    __syncthreads();
    if (tid == 0) T[b] = (unsigned)Tf;
}

// ---------------- pass 2: recompute-compact keys with bin >= T --------------
template<int HW4, int NF4, int LVOFF>
__device__ __forceinline__ void compact_level(const float* lgb, const float* ctb,
        int tid, int lane, int bx, int gx, unsigned Tb, float xpre,
        unsigned* cntb, unsigned long long* selb, unsigned long long ltmask) {
    for (int i0 = bx * 256; i0 < NF4; i0 += gx * 256) {
        int i = i0 + tid;
        bool f0 = false, f1 = false, f2 = false, f3 = false;
        unsigned long long k0 = 0, k1 = 0, k2 = 0, k3 = 0;
        if (i < NF4) {
            int c   = i / HW4;
            int hwf = i - c * HW4;
            float4 v = *(const float4*)(lgb + c * (HW4 * 4) + hwf * 4);
            if (v.x > xpre || v.y > xpre || v.z > xpre || v.w > xpre) {
                float4 cv = *(const float4*)(ctb + hwf * 4);
                int nbase = LVOFF + hwf * 4;
#define DO_J(J, X, CT, F, K)                                                  \
                if ((X) > xpre) {                                             \
                    float cls = 1.0f / (1.0f + expf(-(X)));                   \
                    if (cls > 0.05f) {                                        \
                        float cen = 1.0f / (1.0f + expf(-(CT)));              \
                        float comb = cls * cen;                               \
                        unsigned bits = __float_as_uint(comb);                \
                        if ((bits >> 19) >= Tb) {                             \
                            unsigned idx = (unsigned)((nbase + (J)) * NC + c);\
                            K = ((unsigned long long)bits << 32) |            \
                                (0xFFFFFFFFu - idx);                          \
                            F = true;                                         \
                        }                                                     \
                    }                                                         \
                }
                DO_J(0, v.x, cv.x, f0, k0)
                DO_J(1, v.y, cv.y, f1, k1)
                DO_J(2, v.z, cv.z, f2, k2)
                DO_J(3, v.w, cv.w, f3, k3)
#undef DO_J
            }
        }
        unsigned long long m0 = __ballot(f0), m1 = __ballot(f1);
        unsigned long long m2 = __ballot(f2), m3 = __ballot(f3);
        if ((m0 | m1 | m2 | m3) == 0ULL) continue;   // wave-uniform skip
        unsigned t0 = (unsigned)__popcll(m0), t1 = (unsigned)__popcll(m1);
        unsigned t2 = (unsigned)__popcll(m2), t3 = (unsigned)__popcll(m3);
        unsigned total = t0 + t1 + t2 + t3;
        int basep = 0;
        if (lane == 0) basep = (int)atomicAdd(cntb, total);
        basep = __shfl(basep, 0);
        if (f0) { int pos = basep + (int)__popcll(m0 & ltmask);                       if (pos < CAP) selb[pos] = k0; }
        if (f1) { int pos = basep + (int)t0 + (int)__popcll(m1 & ltmask);             if (pos < CAP) selb[pos] = k1; }
        if (f2) { int pos = basep + (int)(t0 + t1) + (int)__popcll(m2 & ltmask);      if (pos < CAP) selb[pos] = k2; }
        if (f3) { int pos = basep + (int)(t0 + t1 + t2) + (int)__popcll(m3 & ltmask); if (pos < CAP) selb[pos] = k3; }
    }
}

__global__ void __launch_bounds__(256) k_compactB(Ptrs p, const unsigned* T,
                                                  unsigned* cnt2, unsigned long long* sel) {
    int b = blockIdx.y, tid = threadIdx.x, lane = tid & 63;
    int bx = blockIdx.x, gx = gridDim.x;
    unsigned Tb = T[b];
    // logit-space prefilter: bin >= T => comb >= m => cls > m (cen < 1)
    //  => x > logit(m). 0.01 margin absorbs logf rounding; exact checks follow.
    float mthr = __uint_as_float(Tb << 19);
    float xpre = -2.95f;
    if (mthr > 1e-37f && mthr < 1.0f) {
        float lm = logf(mthr / (1.0f - mthr)) - 0.01f;
        if (lm > xpre) xpre = lm;
    }
    unsigned long long ltmask = (1ULL << lane) - 1ULL;
    unsigned* cntb = cnt2 + (size_t)b * CNTSTRIDE;
    unsigned long long* selb = sel + (size_t)b * CAP;
    compact_level<3200, 256000,     0>(p.lg[0] + (size_t)b * NC * 12800, p.ct[0] + (size_t)b * 12800, tid, lane, bx, gx, Tb, xpre, cntb, selb, ltmask);
    compact_level< 800,  64000, 12800>(p.lg[1] + (size_t)b * NC * 3200,  p.ct[1] + (size_t)b * 3200,  tid, lane, bx, gx, Tb, xpre, cntb, selb, ltmask);
    compact_level< 200,  16000, 16000>(p.lg[2] + (size_t)b * NC * 800,   p.ct[2] + (size_t)b * 800,   tid, lane, bx, gx, Tb, xpre, cntb, selb, ltmask);
    compact_level<  52,   4160, 16800>(p.lg[3] + (size_t)b * NC * 208,   p.ct[3] + (size_t)b * 208,   tid, lane, bx, gx, Tb, xpre, cntb, selb, ltmask);
    compact_level<  14,   1120, 17008>(p.lg[4] + (size_t)b * NC * 56,    p.ct[4] + (size_t)b * 56,    tid, lane, bx, gx, Tb, xpre, cntb, selb, ltmask);
}

// ---------------- fused rank + decode + scan-NMS ----------------------------
// One block/batch, 1024 threads. Phase 1: exact rank of each unique key
// (rank = #{keys > k}) via wave-broadcast LDS reads — no sort, 2 barriers.
// Phase 2: decode rank<TOPK candidates into rank-indexed LDS arrays.
// Phase 3: wave 0 alone scans candidates in rank order, accepting any not
// suppressed (IoU>=0.6) by the accepted list — provably identical to the
// reference's iterative argmax-suppress (picks occur in rank order; suppression
// is permanent; IoU operands identical; fmax symmetric). Accepted boxes live
// in 2 register slots/lane; zero barriers in the scan.
__global__ void __launch_bounds__(1024) k_selnms(Ptrs p, const unsigned* cnt,
                                                 const unsigned long long* sel,
                                                 const float* im_info, float* out) {
    __shared__ __align__(16) unsigned long long keys[CAP + 2];
    __shared__ float4 nbx[TOPK];
    __shared__ float  sarea[TOPK];
    __shared__ float4 obox[TOPK];
    __shared__ float2 oscl[TOPK];
    int b = blockIdx.x, tid = threadIdx.x, lane = tid & 63;

    unsigned M = cnt[(size_t)b * CNTSTRIDE];
    if (M > CAP) M = CAP;
    int Mpad = (int)((M + 1u) & ~1u);
    for (int i = tid; i < Mpad; i += 1024)
        keys[i] = (i < (int)M) ? sel[(size_t)b * CAP + i] : 0ULL;
    __syncthreads();

    float Him = im_info[b * 2 + 0], Wim = im_info[b * 2 + 1];
    float xmax = Wim - 1.0f, ymax = Him - 1.0f;

    for (int i = tid; i < (int)M; i += 1024) {
        unsigned long long k = keys[i];
        int rank = 0;
        for (int j = 0; j < Mpad; j += 2) {
            ulonglong2 kk = *(const ulonglong2*)&keys[j];   // wave-broadcast
            rank += (kk.x > k) ? 1 : 0;
            rank += (kk.y > k) ? 1 : 0;
        }
        if (rank < TOPK) {
            unsigned sb = (unsigned)(k >> 32);
            unsigned idx = 0xFFFFFFFFu - (unsigned)(k & 0xFFFFFFFFu);
            float val = __uint_as_float(sb);
            int n = idx / NC, c = idx - n * NC;
            int l, hw, W, stride, half, HW;
            level_of(n, l, hw, W, stride, half, HW);
            int wx = hw % W, hy = hw / W;
            float locx = (float)(wx * stride + half);
            float locy = (float)(hy * stride + half);
            const float* bb = p.bb[l] + (size_t)b * 4 * HW + hw;
            float r0 = bb[0], r1 = bb[(size_t)HW], r2 = bb[(size_t)2 * HW], r3 = bb[(size_t)3 * HW];
            float x1 = locx - r0, y1 = locy - r1, x2 = locx + r2, y2 = locy + r3;
            x1 = fminf(fmaxf(x1, 0.f), xmax);
            y1 = fminf(fmaxf(y1, 0.f), ymax);
            x2 = fminf(fmaxf(x2, 0.f), xmax);
            y2 = fminf(fmaxf(y2, 0.f), ymax);
            float s = sqrtf(val + 1e-12f);
            float off = (float)c * 10000.0f;
            float a0 = x1 + off, a1 = y1 + off, a2 = x2 + off, a3 = y2 + off;
            nbx[rank] = make_float4(a0, a1, a2, a3);
            sarea[rank] = fmaxf(a2 - a0, 0.f) * fmaxf(a3 - a1, 0.f);
            obox[rank] = make_float4(x1, y1, x2, y2);
            oscl[rank] = make_float2(s, (float)c);
        }
    }
    __syncthreads();
    if (tid >= 64) return;                       // wave 0 only from here on

    int ncand = (int)M < TOPK ? (int)M : TOPK;
    int na = 0;
    float4 a0b = make_float4(0.f, 0.f, 0.f, 0.f);
    float4 a1b = make_float4(0.f, 0.f, 0.f, 0.f);
    float a0a = 0.f, a1a = 0.f;
    float* ob = out + (size_t)b * MAXDET * 6;

    for (int r = 0; r < ncand && na < MAXDET; ++r) {
        float4 cb = nbx[r];                      // broadcast LDS read
        float ca = sarea[r];
        bool sup = false;
        if (lane < na) {
            float xx1 = fmaxf(a0b.x, cb.x);
            float yy1 = fmaxf(a0b.y, cb.y);
            float xx2 = fminf(a0b.z, cb.z);
            float yy2 = fminf(a0b.w, cb.w);
            float inter = fmaxf(xx2 - xx1, 0.f) * fmaxf(yy2 - yy1, 0.f);
            float iou = inter / (((a0a + ca) - inter) + 1e-9f);
            sup = (iou >= 0.6f);
        }
        if (lane + 64 < na) {
            float xx1 = fmaxf(a1b.x, cb.x);
            float yy1 = fmaxf(a1b.y, cb.y);
            float xx2 = fminf(a1b.z, cb.z);
            float yy2 = fminf(a1b.w, cb.w);
            float inter = fmaxf(xx2 - xx1, 0.f) * fmaxf(yy2 - yy1, 0.f);
            float iou = inter / (((a1a + ca) - inter) + 1e-9f);
            sup |= (iou >= 0.6f);
        }
        if (__ballot(sup) == 0ULL) {             // accepted
            if (lane == (na & 63)) {
                if (na < 64) { a0b = cb; a0a = ca; }
                else         { a1b = cb; a1a = ca; }
            }
            if (lane == 0) {
                float4 o4 = obox[r]; float2 s2 = oscl[r];
                ob[na * 6 + 0] = o4.x; ob[na * 6 + 1] = o4.y;
                ob[na * 6 + 2] = o4.z; ob[na * 6 + 3] = o4.w;
                ob[na * 6 + 4] = s2.x; ob[na * 6 + 5] = s2.y;
            }
            ++na;
        }
    }
    for (int q = na * 6 + lane; q < MAXDET * 6; q += 64)
        ob[q] = 0.f;
}

extern "C" void kernel_launch(void* const* d_in, const int* in_sizes, int n_in,
                              void* d_out, int out_size, void* d_ws, size_t ws_size,
                              hipStream_t stream) {
    Ptrs p;
    for (int l = 0; l < 5; ++l) {
        p.lg[l] = (const float*)d_in[3 * l + 0];
        p.bb[l] = (const float*)d_in[3 * l + 1];
        p.ct[l] = (const float*)d_in[3 * l + 2];
    }
    const float* im_info = (const float*)d_in[15];
    float* out = (float*)d_out;

    unsigned char* w = (unsigned char*)d_ws;
    // layout: [hist 4*16*32KB = 2,097,152 | cnt2 4096 | T 256] zeroed, then sel
    unsigned* hist          = (unsigned*)(w);
    unsigned* cnt2          = (unsigned*)(w + 2097152);
    unsigned* T             = (unsigned*)(w + 2101248);
    unsigned long long* sel = (unsigned long long*)(w + 2101504);  // 16*4096*8

    hipMemsetAsync(w, 0, 2101504, stream);

    k_histA<<<dim3(64, NB), 256, 0, stream>>>(p, hist);
    k_thresh<<<NB, 256, 0, stream>>>(hist, T);
    k_compactB<<<dim3(128, NB), 256, 0, stream>>>(p, T, cnt2, sel);
    k_selnms<<<NB, 1024, 0, stream>>>(p, cnt2, sel, im_info, out);
}

// Round 8
// 254.968 us; speedup vs baseline: 1.4115x; 1.0368x over previous
//
#include <hip/hip_runtime.h>
#include <math.h>

#pragma clang fp contract(off)

#define NB 16
#define NC 80
#define NTOT 17064
#define TOPK 1000
#define NBINS 8192
#define CAP 4096
#define MAXDET 100
#define NREP 2           // histogram replicas (spread flush atomics)
#define CNTSTRIDE 64     // u32 stride between per-batch counters = 256 B
#define CHUNK 128        // NMS staging chunk

struct Ptrs {
    const float* lg[5];
    const float* bb[5];
    const float* ct[5];
};

__device__ __forceinline__ void level_of(int n, int& l, int& hw, int& W,
                                         int& stride, int& half, int& HW) {
    if (n < 12800)      { l = 0; hw = n;         W = 128; stride = 8;   half = 4;  HW = 12800; }
    else if (n < 16000) { l = 1; hw = n - 12800; W = 64;  stride = 16;  half = 8;  HW = 3200;  }
    else if (n < 16800) { l = 2; hw = n - 16000; W = 32;  stride = 32;  half = 16; HW = 800;   }
    else if (n < 17008) { l = 3; hw = n - 16800; W = 16;  stride = 64;  half = 32; HW = 208;   }
    else                { l = 4; hw = n - 17008; W = 8;   stride = 128; half = 64; HW = 56;    }
}

// ---------------- pass 1: histogram sweep (per-level, compile-time const) ---
template<int HW4, int NF4>
__device__ __forceinline__ void hist_level(const float* lgb, const float* ctb,
                                           int tid, int bx, int gx, unsigned* lh) {
    for (int i0 = bx * 256; i0 < NF4; i0 += gx * 256) {
        int i = i0 + tid;
        if (i < NF4) {
            int c   = i / HW4;            // constant divisor -> magic mul
            int hwf = i - c * HW4;
            float4 v  = *(const float4*)(lgb + c * (HW4 * 4) + hwf * 4);
            if (v.x > -2.95f || v.y > -2.95f || v.z > -2.95f || v.w > -2.95f) {
                float4 cv = *(const float4*)(ctb + hwf * 4);
                float xs[4] = {v.x, v.y, v.z, v.w};
                float cs[4] = {cv.x, cv.y, cv.z, cv.w};
#pragma unroll
                for (int j = 0; j < 4; ++j) {
                    float x = xs[j];
                    if (x > -2.95f) {             // logit(0.05) = -2.9444
                        float cls = 1.0f / (1.0f + expf(-x));
                        if (cls > 0.05f) {
                            float cen = 1.0f / (1.0f + expf(-cs[j]));
                            float comb = cls * cen;
                            atomicAdd(&lh[__float_as_uint(comb) >> 19], 1u);
                        }
                    }
                }
            }
        }
    }
}

__global__ void __launch_bounds__(256) k_histA(Ptrs p, unsigned* hist) {
    __shared__ unsigned lh[NBINS];   // 32 KiB
    int b = blockIdx.y, tid = threadIdx.x, bx = blockIdx.x, gx = gridDim.x;
    for (int i = tid; i < NBINS; i += 256) lh[i] = 0;
    __syncthreads();

    hist_level<3200, 256000>(p.lg[0] + (size_t)b * NC * 12800, p.ct[0] + (size_t)b * 12800, tid, bx, gx, lh);
    hist_level< 800,  64000>(p.lg[1] + (size_t)b * NC * 3200,  p.ct[1] + (size_t)b * 3200,  tid, bx, gx, lh);
    hist_level< 200,  16000>(p.lg[2] + (size_t)b * NC * 800,   p.ct[2] + (size_t)b * 800,   tid, bx, gx, lh);
    hist_level<  52,   4160>(p.lg[3] + (size_t)b * NC * 208,   p.ct[3] + (size_t)b * 208,   tid, bx, gx, lh);
    hist_level<  14,   1120>(p.lg[4] + (size_t)b * NC * 56,    p.ct[4] + (size_t)b * 56,    tid, bx, gx, lh);

    __syncthreads();
    unsigned* h = hist + ((size_t)(bx & (NREP - 1)) * NB + b) * NBINS;
    for (int i = tid; i < NBINS; i += 256) {
        unsigned v = lh[i];
        if (v) atomicAdd(&h[i], v);
    }
}

// ---------------- threshold: highest bin with suffix count >= TOPK ----------
__global__ void __launch_bounds__(256) k_thresh(const unsigned* hist, unsigned* T) {
    __shared__ unsigned hl[NBINS];
    __shared__ unsigned wtot[4];
    __shared__ int Tf;
    int b = blockIdx.x, tid = threadIdx.x, lane = tid & 63, wv = tid >> 6;
    if (tid == 0) Tf = 0;
    for (int i = tid; i < NBINS; i += 256) {
        unsigned s = 0;
        for (int r = 0; r < NREP; ++r)
            s += hist[((size_t)r * NB + b) * NBINS + i];
        hl[i] = s;
    }
    __syncthreads();
    int base = tid * 32;
    unsigned mysum = 0;
#pragma unroll
    for (int i = 0; i < 32; ++i) mysum += hl[base + i];
    unsigned incl = mysum;                      // suffix-inclusive within wave
#pragma unroll
    for (int off = 1; off < 64; off <<= 1) {
        unsigned v = __shfl_down(incl, off);
        if (lane + off < 64) incl += v;
    }
    if (lane == 0) wtot[wv] = incl;             // whole-wave total
    __syncthreads();
    unsigned above = 0;
    for (int w = wv + 1; w < 4; ++w) above += wtot[w];
    unsigned sufincl = incl + above;            // sum of chunks >= tid
    unsigned excl = sufincl - mysum;            // sum of chunks >  tid
    if (excl < TOPK && sufincl >= TOPK) {
        unsigned running = excl;
        for (int bin = base + 31; bin >= base; --bin) {
            running += hl[bin];
            if (running >= TOPK) { Tf = bin; break; }
        }
    }
    __syncthreads();
    if (tid == 0) T[b] = (unsigned)Tf;
}

// ---------------- pass 2: recompute-compact keys with bin >= T --------------
template<int HW4, int NF4, int LVOFF>
__device__ __forceinline__ void compact_level(const float* lgb, const float* ctb,
        int tid, int lane, int bx, int gx, unsigned Tb, float xpre,
        unsigned* cntb, unsigned long long* selb, unsigned long long ltmask) {
    for (int i0 = bx * 256; i0 < NF4; i0 += gx * 256) {
        int i = i0 + tid;
        bool f0 = false, f1 = false, f2 = false, f3 = false;
        unsigned long long k0 = 0, k1 = 0, k2 = 0, k3 = 0;
        if (i < NF4) {
            int c   = i / HW4;
            int hwf = i - c * HW4;
            float4 v = *(const float4*)(lgb + c * (HW4 * 4) + hwf * 4);
            if (v.x > xpre || v.y > xpre || v.z > xpre || v.w > xpre) {
                float4 cv = *(const float4*)(ctb + hwf * 4);
                int nbase = LVOFF + hwf * 4;
#define DO_J(J, X, CT, F, K)                                                  \
                if ((X) > xpre) {                                             \
                    float cls = 1.0f / (1.0f + expf(-(X)));                   \
                    if (cls > 0.05f) {                                        \
                        float cen = 1.0f / (1.0f + expf(-(CT)));              \
                        float comb = cls * cen;                               \
                        unsigned bits = __float_as_uint(comb);                \
                        if ((bits >> 19) >= Tb) {                             \
                            unsigned idx = (unsigned)((nbase + (J)) * NC + c);\
                            K = ((unsigned long long)bits << 32) |            \
                                (0xFFFFFFFFu - idx);                          \
                            F = true;                                         \
                        }                                                     \
                    }                                                         \
                }
                DO_J(0, v.x, cv.x, f0, k0)
                DO_J(1, v.y, cv.y, f1, k1)
                DO_J(2, v.z, cv.z, f2, k2)
                DO_J(3, v.w, cv.w, f3, k3)
#undef DO_J
            }
        }
        unsigned long long m0 = __ballot(f0), m1 = __ballot(f1);
        unsigned long long m2 = __ballot(f2), m3 = __ballot(f3);
        if ((m0 | m1 | m2 | m3) == 0ULL) continue;   // wave-uniform skip
        unsigned t0 = (unsigned)__popcll(m0), t1 = (unsigned)__popcll(m1);
        unsigned t2 = (unsigned)__popcll(m2), t3 = (unsigned)__popcll(m3);
        unsigned total = t0 + t1 + t2 + t3;
        int basep = 0;
        if (lane == 0) basep = (int)atomicAdd(cntb, total);
        basep = __shfl(basep, 0);
        if (f0) { int pos = basep + (int)__popcll(m0 & ltmask);                       if (pos < CAP) selb[pos] = k0; }
        if (f1) { int pos = basep + (int)t0 + (int)__popcll(m1 & ltmask);             if (pos < CAP) selb[pos] = k1; }
        if (f2) { int pos = basep + (int)(t0 + t1) + (int)__popcll(m2 & ltmask);      if (pos < CAP) selb[pos] = k2; }
        if (f3) { int pos = basep + (int)(t0 + t1 + t2) + (int)__popcll(m3 & ltmask); if (pos < CAP) selb[pos] = k3; }
    }
}

__global__ void __launch_bounds__(256) k_compactB(Ptrs p, const unsigned* T,
                                                  unsigned* cnt2, unsigned long long* sel) {
    int b = blockIdx.y, tid = threadIdx.x, lane = tid & 63;
    int bx = blockIdx.x, gx = gridDim.x;
    unsigned Tb = T[b];
    // logit-space prefilter: bin >= T => comb >= m => cls > m (cen < 1)
    //  => x > logit(m). 0.01 margin absorbs logf rounding; exact checks follow.
    float mthr = __uint_as_float(Tb << 19);
    float xpre = -2.95f;
    if (mthr > 1e-37f && mthr < 1.0f) {
        float lm = logf(mthr / (1.0f - mthr)) - 0.01f;
        if (lm > xpre) xpre = lm;
    }
    unsigned long long ltmask = (1ULL << lane) - 1ULL;
    unsigned* cntb = cnt2 + (size_t)b * CNTSTRIDE;
    unsigned long long* selb = sel + (size_t)b * CAP;
    compact_level<3200, 256000,     0>(p.lg[0] + (size_t)b * NC * 12800, p.ct[0] + (size_t)b * 12800, tid, lane, bx, gx, Tb, xpre, cntb, selb, ltmask);
    compact_level< 800,  64000, 12800>(p.lg[1] + (size_t)b * NC * 3200,  p.ct[1] + (size_t)b * 3200,  tid, lane, bx, gx, Tb, xpre, cntb, selb, ltmask);
    compact_level< 200,  16000, 16000>(p.lg[2] + (size_t)b * NC * 800,   p.ct[2] + (size_t)b * 800,   tid, lane, bx, gx, Tb, xpre, cntb, selb, ltmask);
    compact_level<  52,   4160, 16800>(p.lg[3] + (size_t)b * NC * 208,   p.ct[3] + (size_t)b * 208,   tid, lane, bx, gx, Tb, xpre, cntb, selb, ltmask);
    compact_level<  14,   1120, 17008>(p.lg[4] + (size_t)b * NC * 56,    p.ct[4] + (size_t)b * 56,    tid, lane, bx, gx, Tb, xpre, cntb, selb, ltmask);
}

// ---------------- rank + decode (distributed across CUs) --------------------
// Grid: 16 slices x NB batches, 256 thr. Each block stages all M keys in LDS,
// exactly ranks its 256-key slice (rank = #{keys > k}: total order = value
// desc, index asc), and decodes rank<TOPK candidates into cand[b][rank]:
// [obox.xyzw | nbx.xyzw | area, score, cls, pad] (48 B, float4-aligned).
__global__ void __launch_bounds__(256) k_rankdec(Ptrs p, const unsigned* cnt,
                                                 const unsigned long long* sel,
                                                 const float* im_info, float* cand) {
    __shared__ __align__(16) unsigned long long keys[CAP];
    int b = blockIdx.y, tid = threadIdx.x;
    unsigned M = cnt[(size_t)b * CNTSTRIDE];
    if (M > CAP) M = CAP;
    int s0 = blockIdx.x * 256;
    if (s0 >= (int)M) return;
    int Mpad = (int)((M + 1u) & ~1u);
    for (int i = tid; i < Mpad; i += 256)
        keys[i] = (i < (int)M) ? sel[(size_t)b * CAP + i] : 0ULL;
    __syncthreads();

    int s = s0 + tid;
    if (s >= (int)M) return;
    unsigned long long k = keys[s];
    int rank = 0;
    for (int j = 0; j < Mpad; j += 2) {
        ulonglong2 kk = *(const ulonglong2*)&keys[j];   // wave-broadcast b128
        rank += (kk.x > k) ? 1 : 0;
        rank += (kk.y > k) ? 1 : 0;
    }
    if (rank >= TOPK) return;

    float Him = im_info[b * 2 + 0], Wim = im_info[b * 2 + 1];
    float xmax = Wim - 1.0f, ymax = Him - 1.0f;
    unsigned sb = (unsigned)(k >> 32);
    unsigned idx = 0xFFFFFFFFu - (unsigned)(k & 0xFFFFFFFFu);
    float val = __uint_as_float(sb);
    int n = idx / NC, c = idx - n * NC;
    int l, hw, W, stride, half, HW;
    level_of(n, l, hw, W, stride, half, HW);
    int wx = hw % W, hy = hw / W;
    float locx = (float)(wx * stride + half);
    float locy = (float)(hy * stride + half);
    const float* bb = p.bb[l] + (size_t)b * 4 * HW + hw;
    float r0 = bb[0], r1 = bb[(size_t)HW], r2 = bb[(size_t)2 * HW], r3 = bb[(size_t)3 * HW];
    float x1 = locx - r0, y1 = locy - r1, x2 = locx + r2, y2 = locy + r3;
    x1 = fminf(fmaxf(x1, 0.f), xmax);
    y1 = fminf(fmaxf(y1, 0.f), ymax);
    x2 = fminf(fmaxf(x2, 0.f), xmax);
    y2 = fminf(fmaxf(y2, 0.f), ymax);
    float scv = sqrtf(val + 1e-12f);
    float off = (float)c * 10000.0f;
    float a0 = x1 + off, a1 = y1 + off, a2 = x2 + off, a3 = y2 + off;
    float area = fmaxf(a2 - a0, 0.f) * fmaxf(a3 - a1, 0.f);
    float* dst = cand + ((size_t)b * TOPK + rank) * 12;
    *(float4*)(dst + 0) = make_float4(x1, y1, x2, y2);
    *(float4*)(dst + 4) = make_float4(a0, a1, a2, a3);
    *(float4*)(dst + 8) = make_float4(area, scv, (float)c, 0.f);
}

// ---------------- scan-NMS (one wave per batch) -----------------------------
// Candidates arrive in exact rank order; greedy argmax-suppress == scan in
// rank order accepting any candidate not suppressed by the accepted list
// (suppression permanent, picks occur in rank order, IoU operands identical).
// Accepted boxes in 2 register slots/lane; 128-candidate LDS chunks.
__global__ void __launch_bounds__(64) k_nms(const unsigned* cnt, const float* cand,
                                            float* out) {
    __shared__ float4 s_ob[CHUNK], s_nb[CHUNK], s_ms[CHUNK];
    int b = blockIdx.x, lane = threadIdx.x;
    unsigned M = cnt[(size_t)b * CNTSTRIDE];
    if (M > CAP) M = CAP;
    int ncand = (int)M < TOPK ? (int)M : TOPK;
    const float* src = cand + (size_t)b * TOPK * 12;
    float* ob = out + (size_t)b * MAXDET * 6;

    int na = 0;
    float4 a0b = make_float4(0.f, 0.f, 0.f, 0.f);
    float4 a1b = make_float4(0.f, 0.f, 0.f, 0.f);
    float a0a = 0.f, a1a = 0.f;

    for (int base = 0; base < ncand && na < MAXDET; base += CHUNK) {
        int cn = ncand - base; if (cn > CHUNK) cn = CHUNK;
        for (int cidx = lane; cidx < cn; cidx += 64) {
            const float* s = src + (size_t)(base + cidx) * 12;
            s_ob[cidx] = *(const float4*)(s + 0);
            s_nb[cidx] = *(const float4*)(s + 4);
            s_ms[cidx] = *(const float4*)(s + 8);
        }
        __syncthreads();
        for (int r = 0; r < cn && na < MAXDET; ++r) {
            float4 cb = s_nb[r];                 // broadcast LDS read
            float ca = s_ms[r].x;
            bool sup = false;
            if (lane < na) {
                float xx1 = fmaxf(a0b.x, cb.x);
                float yy1 = fmaxf(a0b.y, cb.y);
                float xx2 = fminf(a0b.z, cb.z);
                float yy2 = fminf(a0b.w, cb.w);
                float inter = fmaxf(xx2 - xx1, 0.f) * fmaxf(yy2 - yy1, 0.f);
                float iou = inter / (((a0a + ca) - inter) + 1e-9f);
                sup = (iou >= 0.6f);
            }
            if (lane + 64 < na) {
                float xx1 = fmaxf(a1b.x, cb.x);
                float yy1 = fmaxf(a1b.y, cb.y);
                float xx2 = fminf(a1b.z, cb.z);
                float yy2 = fminf(a1b.w, cb.w);
                float inter = fmaxf(xx2 - xx1, 0.f) * fmaxf(yy2 - yy1, 0.f);
                float iou = inter / (((a1a + ca) - inter) + 1e-9f);
                sup |= (iou >= 0.6f);
            }
            if (__ballot(sup) == 0ULL) {         // accepted
                if (lane == (na & 63)) {
                    if (na < 64) { a0b = cb; a0a = ca; }
                    else         { a1b = cb; a1a = ca; }
                }
                if (lane == 0) {
                    float4 o4 = s_ob[r]; float4 m4 = s_ms[r];
                    ob[na * 6 + 0] = o4.x; ob[na * 6 + 1] = o4.y;
                    ob[na * 6 + 2] = o4.z; ob[na * 6 + 3] = o4.w;
                    ob[na * 6 + 4] = m4.y; ob[na * 6 + 5] = m4.z;
                }
                ++na;
            }
        }
        __syncthreads();
    }
    for (int q = na * 6 + lane; q < MAXDET * 6; q += 64)
        ob[q] = 0.f;
}

extern "C" void kernel_launch(void* const* d_in, const int* in_sizes, int n_in,
                              void* d_out, int out_size, void* d_ws, size_t ws_size,
                              hipStream_t stream) {
    Ptrs p;
    for (int l = 0; l < 5; ++l) {
        p.lg[l] = (const float*)d_in[3 * l + 0];
        p.bb[l] = (const float*)d_in[3 * l + 1];
        p.ct[l] = (const float*)d_in[3 * l + 2];
    }
    const float* im_info = (const float*)d_in[15];
    float* out = (float*)d_out;

    unsigned char* w = (unsigned char*)d_ws;
    // layout: [hist 2*16*32KB = 1,048,576 | cnt2 4096 | T 256] zeroed,
    //         sel 524,288 | cand 768,000  -> total 2,345,216
    unsigned* hist          = (unsigned*)(w);
    unsigned* cnt2          = (unsigned*)(w + 1048576);
    unsigned* T             = (unsigned*)(w + 1052672);
    unsigned long long* sel = (unsigned long long*)(w + 1052928);
    float* cand             = (float*)(w + 1577216);

    hipMemsetAsync(w, 0, 1052928, stream);

    k_histA<<<dim3(64, NB), 256, 0, stream>>>(p, hist);
    k_thresh<<<NB, 256, 0, stream>>>(hist, T);
    k_compactB<<<dim3(128, NB), 256, 0, stream>>>(p, T, cnt2, sel);
    k_rankdec<<<dim3(16, NB), 256, 0, stream>>>(p, cnt2, sel, im_info, cand);
    k_nms<<<NB, 64, 0, stream>>>(cnt2, cand, out);
}

// Round 9
// 241.429 us; speedup vs baseline: 1.4906x; 1.0561x over previous
//
#include <hip/hip_runtime.h>
#include <math.h>

#pragma clang fp contract(off)

#define NB 16
#define NC 80
#define NTOT 17064
#define TOPK 1000
#define NBINS 8192
#define CAP 4096
#define MAXDET 100
#define NREP 2           // histogram replicas (spread flush atomics)
#define CNTSTRIDE 64     // u32 stride between per-batch counters = 256 B
#define CHUNK 128        // NMS staging chunk

struct Ptrs {
    const float* lg[5];
    const float* bb[5];
    const float* ct[5];
};

__device__ __forceinline__ void level_of(int n, int& l, int& hw, int& W,
                                         int& stride, int& half, int& HW) {
    if (n < 12800)      { l = 0; hw = n;         W = 128; stride = 8;   half = 4;  HW = 12800; }
    else if (n < 16000) { l = 1; hw = n - 12800; W = 64;  stride = 16;  half = 8;  HW = 3200;  }
    else if (n < 16800) { l = 2; hw = n - 16000; W = 32;  stride = 32;  half = 16; HW = 800;   }
    else if (n < 17008) { l = 3; hw = n - 16800; W = 16;  stride = 64;  half = 32; HW = 208;   }
    else                { l = 4; hw = n - 17008; W = 8;   stride = 128; half = 64; HW = 56;    }
}

// Fast HW sigmoid: v_exp_f32 + v_rcp_f32 (~3 instr). Error <= ~15 ulp on the
// product of two of these — used ONLY for the histogram with conservative
// binning (see below). Exact keys still use precise expf + IEEE div.
__device__ __forceinline__ float fast_sig(float x) {
    float e = __expf(-x);
    return __builtin_amdgcn_rcpf(1.0f + e);
}

// ---------------- pass 1: histogram sweep (fast-sigmoid, conservative) ------
// Conservative binning: bin = (comb_fast_bits - 32) >> 19. Since
// |comb_fast - comb_exact| <= ~15 ulp << 32, every element bins at
// bin_exact or bin_exact-1 (never higher) => T_apx in {T_true-1, T_true},
// so compactB (exact keys, bin >= T_apx) always captures the true top-1000.
// Inclusion (cls > 0.05) uses a +-1e-5 guard band (500x fast-path error)
// with precise recompute inside the band -> membership matches reference.
template<int HW4, int NF4>
__device__ __forceinline__ void hist_level(const float* lgb, const float* ctb,
                                           int tid, int bx, int gx, unsigned* lh) {
    for (int i0 = bx * 256; i0 < NF4; i0 += gx * 256) {
        int i = i0 + tid;
        if (i < NF4) {
            int c   = i / HW4;            // constant divisor -> magic mul
            int hwf = i - c * HW4;
            float4 v  = *(const float4*)(lgb + c * (HW4 * 4) + hwf * 4);
            if (v.x > -2.95f || v.y > -2.95f || v.z > -2.95f || v.w > -2.95f) {
                float4 cv = *(const float4*)(ctb + hwf * 4);
                float xs[4] = {v.x, v.y, v.z, v.w};
                float cs[4] = {cv.x, cv.y, cv.z, cv.w};
#pragma unroll
                for (int j = 0; j < 4; ++j) {
                    float x = xs[j];
                    if (x > -2.95f) {             // logit(0.05) = -2.9444
                        float cls = fast_sig(x);
                        if (cls > 0.04999f) {
                            bool in = true;
                            if (cls < 0.05001f) { // guard band: exact recheck
                                float ex = 1.0f / (1.0f + expf(-x));
                                in = ex > 0.05f;
                            }
                            if (in) {
                                float cen = fast_sig(cs[j]);
                                float comb = cls * cen;
                                unsigned bits = __float_as_uint(comb);
                                bits = (bits > 32u) ? bits - 32u : 0u;
                                atomicAdd(&lh[bits >> 19], 1u);
                            }
                        }
                    }
                }
            }
        }
    }
}

__global__ void __launch_bounds__(256) k_histA(Ptrs p, unsigned* hist) {
    __shared__ unsigned lh[NBINS];   // 32 KiB
    int b = blockIdx.y, tid = threadIdx.x, bx = blockIdx.x, gx = gridDim.x;
    for (int i = tid; i < NBINS; i += 256) lh[i] = 0;
    __syncthreads();

    hist_level<3200, 256000>(p.lg[0] + (size_t)b * NC * 12800, p.ct[0] + (size_t)b * 12800, tid, bx, gx, lh);
    hist_level< 800,  64000>(p.lg[1] + (size_t)b * NC * 3200,  p.ct[1] + (size_t)b * 3200,  tid, bx, gx, lh);
    hist_level< 200,  16000>(p.lg[2] + (size_t)b * NC * 800,   p.ct[2] + (size_t)b * 800,   tid, bx, gx, lh);
    hist_level<  52,   4160>(p.lg[3] + (size_t)b * NC * 208,   p.ct[3] + (size_t)b * 208,   tid, bx, gx, lh);
    hist_level<  14,   1120>(p.lg[4] + (size_t)b * NC * 56,    p.ct[4] + (size_t)b * 56,    tid, bx, gx, lh);

    __syncthreads();
    unsigned* h = hist + ((size_t)(bx & (NREP - 1)) * NB + b) * NBINS;
    for (int i = tid; i < NBINS; i += 256) {
        unsigned v = lh[i];
        if (v) atomicAdd(&h[i], v);
    }
}

// ---------------- threshold: highest bin with suffix count >= TOPK ----------
__global__ void __launch_bounds__(256) k_thresh(const unsigned* hist, unsigned* T) {
    __shared__ unsigned hl[NBINS];
    __shared__ unsigned wtot[4];
    __shared__ int Tf;
    int b = blockIdx.x, tid = threadIdx.x, lane = tid & 63, wv = tid >> 6;
    if (tid == 0) Tf = 0;
    for (int i = tid; i < NBINS; i += 256) {
        unsigned s = 0;
        for (int r = 0; r < NREP; ++r)
            s += hist[((size_t)r * NB + b) * NBINS + i];
        hl[i] = s;
    }
    __syncthreads();
    int base = tid * 32;
    unsigned mysum = 0;
#pragma unroll
    for (int i = 0; i < 32; ++i) mysum += hl[base + i];
    unsigned incl = mysum;                      // suffix-inclusive within wave
#pragma unroll
    for (int off = 1; off < 64; off <<= 1) {
        unsigned v = __shfl_down(incl, off);
        if (lane + off < 64) incl += v;
    }
    if (lane == 0) wtot[wv] = incl;             // whole-wave total
    __syncthreads();
    unsigned above = 0;
    for (int w = wv + 1; w < 4; ++w) above += wtot[w];
    unsigned sufincl = incl + above;            // sum of chunks >= tid
    unsigned excl = sufincl - mysum;            // sum of chunks >  tid
    if (excl < TOPK && sufincl >= TOPK) {
        unsigned running = excl;
        for (int bin = base + 31; bin >= base; --bin) {
            running += hl[bin];
            if (running >= TOPK) { Tf = bin; break; }
        }
    }
    __syncthreads();
    if (tid == 0) T[b] = (unsigned)Tf;
}

// ---------------- pass 2: recompute-compact keys with bin >= T --------------
template<int HW4, int NF4, int LVOFF>
__device__ __forceinline__ void compact_level(const float* lgb, const float* ctb,
        int tid, int lane, int bx, int gx, unsigned Tb, float xpre,
        unsigned* cntb, unsigned long long* selb, unsigned long long ltmask) {
    for (int i0 = bx * 256; i0 < NF4; i0 += gx * 256) {
        int i = i0 + tid;
        bool f0 = false, f1 = false, f2 = false, f3 = false;
        unsigned long long k0 = 0, k1 = 0, k2 = 0, k3 = 0;
        if (i < NF4) {
            int c   = i / HW4;
            int hwf = i - c * HW4;
            float4 v = *(const float4*)(lgb + c * (HW4 * 4) + hwf * 4);
            if (v.x > xpre || v.y > xpre || v.z > xpre || v.w > xpre) {
                float4 cv = *(const float4*)(ctb + hwf * 4);
                int nbase = LVOFF + hwf * 4;
#define DO_J(J, X, CT, F, K)                                                  \
                if ((X) > xpre) {                                             \
                    float cls = 1.0f / (1.0f + expf(-(X)));                   \
                    if (cls > 0.05f) {                                        \
                        float cen = 1.0f / (1.0f + expf(-(CT)));              \
                        float comb = cls * cen;                               \
                        unsigned bits = __float_as_uint(comb);                \
                        if ((bits >> 19) >= Tb) {                             \
                            unsigned idx = (unsigned)((nbase + (J)) * NC + c);\
                            K = ((unsigned long long)bits << 32) |            \
                                (0xFFFFFFFFu - idx);                          \
                            F = true;                                         \
                        }                                                     \
                    }                                                         \
                }
                DO_J(0, v.x, cv.x, f0, k0)
                DO_J(1, v.y, cv.y, f1, k1)
                DO_J(2, v.z, cv.z, f2, k2)
                DO_J(3, v.w, cv.w, f3, k3)
#undef DO_J
            }
        }
        unsigned long long m0 = __ballot(f0), m1 = __ballot(f1);
        unsigned long long m2 = __ballot(f2), m3 = __ballot(f3);
        if ((m0 | m1 | m2 | m3) == 0ULL) continue;   // wave-uniform skip
        unsigned t0 = (unsigned)__popcll(m0), t1 = (unsigned)__popcll(m1);
        unsigned t2 = (unsigned)__popcll(m2), t3 = (unsigned)__popcll(m3);
        unsigned total = t0 + t1 + t2 + t3;
        int basep = 0;
        if (lane == 0) basep = (int)atomicAdd(cntb, total);
        basep = __shfl(basep, 0);
        if (f0) { int pos = basep + (int)__popcll(m0 & ltmask);                       if (pos < CAP) selb[pos] = k0; }
        if (f1) { int pos = basep + (int)t0 + (int)__popcll(m1 & ltmask);             if (pos < CAP) selb[pos] = k1; }
        if (f2) { int pos = basep + (int)(t0 + t1) + (int)__popcll(m2 & ltmask);      if (pos < CAP) selb[pos] = k2; }
        if (f3) { int pos = basep + (int)(t0 + t1 + t2) + (int)__popcll(m3 & ltmask); if (pos < CAP) selb[pos] = k3; }
    }
}

__global__ void __launch_bounds__(256) k_compactB(Ptrs p, const unsigned* T,
                                                  unsigned* cnt2, unsigned long long* sel) {
    int b = blockIdx.y, tid = threadIdx.x, lane = tid & 63;
    int bx = blockIdx.x, gx = gridDim.x;
    unsigned Tb = T[b];
    // logit-space prefilter: bin >= T => comb >= m => cls > m (cen < 1)
    //  => x > logit(m). 0.01 margin absorbs logf rounding; exact checks follow.
    float mthr = __uint_as_float(Tb << 19);
    float xpre = -2.95f;
    if (mthr > 1e-37f && mthr < 1.0f) {
        float lm = logf(mthr / (1.0f - mthr)) - 0.01f;
        if (lm > xpre) xpre = lm;
    }
    unsigned long long ltmask = (1ULL << lane) - 1ULL;
    unsigned* cntb = cnt2 + (size_t)b * CNTSTRIDE;
    unsigned long long* selb = sel + (size_t)b * CAP;
    compact_level<3200, 256000,     0>(p.lg[0] + (size_t)b * NC * 12800, p.ct[0] + (size_t)b * 12800, tid, lane, bx, gx, Tb, xpre, cntb, selb, ltmask);
    compact_level< 800,  64000, 12800>(p.lg[1] + (size_t)b * NC * 3200,  p.ct[1] + (size_t)b * 3200,  tid, lane, bx, gx, Tb, xpre, cntb, selb, ltmask);
    compact_level< 200,  16000, 16000>(p.lg[2] + (size_t)b * NC * 800,   p.ct[2] + (size_t)b * 800,   tid, lane, bx, gx, Tb, xpre, cntb, selb, ltmask);
    compact_level<  52,   4160, 16800>(p.lg[3] + (size_t)b * NC * 208,   p.ct[3] + (size_t)b * 208,   tid, lane, bx, gx, Tb, xpre, cntb, selb, ltmask);
    compact_level<  14,   1120, 17008>(p.lg[4] + (size_t)b * NC * 56,    p.ct[4] + (size_t)b * 56,    tid, lane, bx, gx, Tb, xpre, cntb, selb, ltmask);
}

// ---------------- rank + decode (distributed across CUs) --------------------
__global__ void __launch_bounds__(256) k_rankdec(Ptrs p, const unsigned* cnt,
                                                 const unsigned long long* sel,
                                                 const float* im_info, float* cand) {
    __shared__ __align__(16) unsigned long long keys[CAP];
    int b = blockIdx.y, tid = threadIdx.x;
    unsigned M = cnt[(size_t)b * CNTSTRIDE];
    if (M > CAP) M = CAP;
    int s0 = blockIdx.x * 256;
    if (s0 >= (int)M) return;
    int Mpad = (int)((M + 1u) & ~1u);
    for (int i = tid; i < Mpad; i += 256)
        keys[i] = (i < (int)M) ? sel[(size_t)b * CAP + i] : 0ULL;
    __syncthreads();

    int s = s0 + tid;
    if (s >= (int)M) return;
    unsigned long long k = keys[s];
    int rank = 0;
    for (int j = 0; j < Mpad; j += 2) {
        ulonglong2 kk = *(const ulonglong2*)&keys[j];   // wave-broadcast b128
        rank += (kk.x > k) ? 1 : 0;
        rank += (kk.y > k) ? 1 : 0;
    }
    if (rank >= TOPK) return;

    float Him = im_info[b * 2 + 0], Wim = im_info[b * 2 + 1];
    float xmax = Wim - 1.0f, ymax = Him - 1.0f;
    unsigned sb = (unsigned)(k >> 32);
    unsigned idx = 0xFFFFFFFFu - (unsigned)(k & 0xFFFFFFFFu);
    float val = __uint_as_float(sb);
    int n = idx / NC, c = idx - n * NC;
    int l, hw, W, stride, half, HW;
    level_of(n, l, hw, W, stride, half, HW);
    int wx = hw % W, hy = hw / W;
    float locx = (float)(wx * stride + half);
    float locy = (float)(hy * stride + half);
    const float* bb = p.bb[l] + (size_t)b * 4 * HW + hw;
    float r0 = bb[0], r1 = bb[(size_t)HW], r2 = bb[(size_t)2 * HW], r3 = bb[(size_t)3 * HW];
    float x1 = locx - r0, y1 = locy - r1, x2 = locx + r2, y2 = locy + r3;
    x1 = fminf(fmaxf(x1, 0.f), xmax);
    y1 = fminf(fmaxf(y1, 0.f), ymax);
    x2 = fminf(fmaxf(x2, 0.f), xmax);
    y2 = fminf(fmaxf(y2, 0.f), ymax);
    float scv = sqrtf(val + 1e-12f);
    float off = (float)c * 10000.0f;
    float a0 = x1 + off, a1 = y1 + off, a2 = x2 + off, a3 = y2 + off;
    float area = fmaxf(a2 - a0, 0.f) * fmaxf(a3 - a1, 0.f);
    float* dst = cand + ((size_t)b * TOPK + rank) * 12;
    *(float4*)(dst + 0) = make_float4(x1, y1, x2, y2);
    *(float4*)(dst + 4) = make_float4(a0, a1, a2, a3);
    *(float4*)(dst + 8) = make_float4(area, scv, (float)c, 0.f);
}

// ---------------- scan-NMS (one wave per batch) -----------------------------
__global__ void __launch_bounds__(64) k_nms(const unsigned* cnt, const float* cand,
                                            float* out) {
    __shared__ float4 s_ob[CHUNK], s_nb[CHUNK], s_ms[CHUNK];
    int b = blockIdx.x, lane = threadIdx.x;
    unsigned M = cnt[(size_t)b * CNTSTRIDE];
    if (M > CAP) M = CAP;
    int ncand = (int)M < TOPK ? (int)M : TOPK;
    const float* src = cand + (size_t)b * TOPK * 12;
    float* ob = out + (size_t)b * MAXDET * 6;

    int na = 0;
    float4 a0b = make_float4(0.f, 0.f, 0.f, 0.f);
    float4 a1b = make_float4(0.f, 0.f, 0.f, 0.f);
    float a0a = 0.f, a1a = 0.f;

    for (int base = 0; base < ncand && na < MAXDET; base += CHUNK) {
        int cn = ncand - base; if (cn > CHUNK) cn = CHUNK;
        for (int cidx = lane; cidx < cn; cidx += 64) {
            const float* s = src + (size_t)(base + cidx) * 12;
            s_ob[cidx] = *(const float4*)(s + 0);
            s_nb[cidx] = *(const float4*)(s + 4);
            s_ms[cidx] = *(const float4*)(s + 8);
        }
        __syncthreads();
        for (int r = 0; r < cn && na < MAXDET; ++r) {
            float4 cb = s_nb[r];                 // broadcast LDS read
            float ca = s_ms[r].x;
            bool sup = false;
            if (lane < na) {
                float xx1 = fmaxf(a0b.x, cb.x);
                float yy1 = fmaxf(a0b.y, cb.y);
                float xx2 = fminf(a0b.z, cb.z);
                float yy2 = fminf(a0b.w, cb.w);
                float inter = fmaxf(xx2 - xx1, 0.f) * fmaxf(yy2 - yy1, 0.f);
                float iou = inter / (((a0a + ca) - inter) + 1e-9f);
                sup = (iou >= 0.6f);
            }
            if (lane + 64 < na) {
                float xx1 = fmaxf(a1b.x, cb.x);
                float yy1 = fmaxf(a1b.y, cb.y);
                float xx2 = fminf(a1b.z, cb.z);
                float yy2 = fminf(a1b.w, cb.w);
                float inter = fmaxf(xx2 - xx1, 0.f) * fmaxf(yy2 - yy1, 0.f);
                float iou = inter / (((a1a + ca) - inter) + 1e-9f);
                sup |= (iou >= 0.6f);
            }
            if (__ballot(sup) == 0ULL) {         // accepted
                if (lane == (na & 63)) {
                    if (na < 64) { a0b = cb; a0a = ca; }
                    else         { a1b = cb; a1a = ca; }
                }
                if (lane == 0) {
                    float4 o4 = s_ob[r]; float4 m4 = s_ms[r];
                    ob[na * 6 + 0] = o4.x; ob[na * 6 + 1] = o4.y;
                    ob[na * 6 + 2] = o4.z; ob[na * 6 + 3] = o4.w;
                    ob[na * 6 + 4] = m4.y; ob[na * 6 + 5] = m4.z;
                }
                ++na;
            }
        }
        __syncthreads();
    }
    for (int q = na * 6 + lane; q < MAXDET * 6; q += 64)
        ob[q] = 0.f;
}

extern "C" void kernel_launch(void* const* d_in, const int* in_sizes, int n_in,
                              void* d_out, int out_size, void* d_ws, size_t ws_size,
                              hipStream_t stream) {
    Ptrs p;
    for (int l = 0; l < 5; ++l) {
        p.lg[l] = (const float*)d_in[3 * l + 0];
        p.bb[l] = (const float*)d_in[3 * l + 1];
        p.ct[l] = (const float*)d_in[3 * l + 2];
    }
    const float* im_info = (const float*)d_in[15];
    float* out = (float*)d_out;

    unsigned char* w = (unsigned char*)d_ws;
    // layout: [hist 2*16*32KB = 1,048,576 | cnt2 4096 | T 256] zeroed,
    //         sel 524,288 | cand 768,000  -> total 2,345,216
    unsigned* hist          = (unsigned*)(w);
    unsigned* cnt2          = (unsigned*)(w + 1048576);
    unsigned* T             = (unsigned*)(w + 1052672);
    unsigned long long* sel = (unsigned long long*)(w + 1052928);
    float* cand             = (float*)(w + 1577216);

    hipMemsetAsync(w, 0, 1052928, stream);

    k_histA<<<dim3(64, NB), 256, 0, stream>>>(p, hist);
    k_thresh<<<NB, 256, 0, stream>>>(hist, T);
    k_compactB<<<dim3(128, NB), 256, 0, stream>>>(p, T, cnt2, sel);
    k_rankdec<<<dim3(16, NB), 256, 0, stream>>>(p, cnt2, sel, im_info, cand);
    k_nms<<<NB, 64, 0, stream>>>(cnt2, cand, out);
}